// Round 2
// baseline (873.242 us; speedup 1.0000x reference)
//
#include <hip/hip_runtime.h>

#define NN 6144
#define BND (NN*16)

typedef short short8 __attribute__((ext_vector_type(8)));
typedef float f32x4 __attribute__((ext_vector_type(4)));

__device__ __forceinline__ short f2bf(float f) {
    unsigned u = __builtin_bit_cast(unsigned, f);
    u = (u + 0x7FFFu + ((u >> 16) & 1u)) >> 16;   // RNE to bf16
    return (short)u;
}

// ---------------- prep: transpose X [8,6144,16] fp32 -> Xt [128][6144] bf16 ----------------
// block: 64 m-rows x 16 d for one b. Coalesced float4 reads, LDS transpose, 16B writes.
__global__ void __launch_bounds__(256) prep_kernel(
    const float* __restrict__ xin, unsigned short* __restrict__ Xt)
{
    __shared__ unsigned short ldsT[16 * 64];
    const int b  = blockIdx.y;
    const int m0 = blockIdx.x * 64;
    const int t  = threadIdx.x;
    const int ml = t >> 2, dq = t & 3;
    float4 v = *(const float4*)(xin + (size_t)b * BND + (size_t)(m0 + ml) * 16 + dq * 4);
    ldsT[(dq * 4 + 0) * 64 + ml] = (unsigned short)f2bf(v.x);
    ldsT[(dq * 4 + 1) * 64 + ml] = (unsigned short)f2bf(v.y);
    ldsT[(dq * 4 + 2) * 64 + ml] = (unsigned short)f2bf(v.z);
    ldsT[(dq * 4 + 3) * 64 + ml] = (unsigned short)f2bf(v.w);
    __syncthreads();
    if (t < 128) {
        int d = t >> 3, j = t & 7;
        short8 s = *(const short8*)&ldsT[d * 64 + j * 8];
        *(short8*)(Xt + (size_t)(b * 16 + d) * NN + m0 + j * 8) = s;
    }
}

// ---------------- main: Y[k][n][c] = (sup_k + I) @ X ----------------
// Block 256 = 4 independent waves. Each wave: 16 rows x 128 cols x K-segment 1536.
// A fp32 straight from HBM -> regs -> bf16; B-frags from L2-resident Xt. No barriers
// in the K-loop. Cross-wave (cross-segment) reduce through LDS at the end.
__global__ void __launch_bounds__(256, 4) gemm_kernel(
    const float* __restrict__ sup, const float* __restrict__ xin,
    const unsigned short* __restrict__ Xt, float* __restrict__ Yws)
{
    __shared__ float lred[4 * 2048];
    const int tid = threadIdx.x;
    const int w = tid >> 6, L = tid & 63, q = L >> 4, col = L & 15;
    const int n0 = blockIdx.x * 16;
    const int k  = blockIdx.y;
    const float* arow = sup + (size_t)k * NN * NN + (size_t)(n0 + col) * NN;
    const unsigned short* xcol = Xt + (size_t)col * NN;

    f32x4 acc[8];
#pragma unroll
    for (int i = 0; i < 8; ++i) acc[i] = (f32x4)0.0f;

    int m0 = w * 1536 + q * 8;   // k-slot offset: identical (q,j) formula for A and B frags
    for (int it = 0; it < 48; ++it, m0 += 32) {
        float4 a0 = *(const float4*)(arow + m0);
        float4 a1 = *(const float4*)(arow + m0 + 4);
        short8 bfr[8];
#pragma unroll
        for (int cc = 0; cc < 8; ++cc)
            bfr[cc] = *(const short8*)(xcol + (size_t)cc * 16 * NN + m0);
        short8 af;
        af[0] = f2bf(a0.x); af[1] = f2bf(a0.y); af[2] = f2bf(a0.z); af[3] = f2bf(a0.w);
        af[4] = f2bf(a1.x); af[5] = f2bf(a1.y); af[6] = f2bf(a1.z); af[7] = f2bf(a1.w);
#pragma unroll
        for (int cc = 0; cc < 8; ++cc)
            acc[cc] = __builtin_amdgcn_mfma_f32_16x16x32_bf16(af, bfr[cc], acc[cc], 0, 0, 0);
    }

    // C/D layout: col = lane&15, row = q*4 + reg (m89-verified). Stash per-segment tile.
#pragma unroll
    for (int cc = 0; cc < 8; ++cc)
#pragma unroll
        for (int r = 0; r < 4; ++r)
            lred[w * 2048 + (q * 4 + r) * 128 + cc * 16 + col] = acc[cc][r];
    __syncthreads();

    // Sum 4 segments, add identity (fp32 X), write coalesced float4.
#pragma unroll
    for (int half = 0; half < 2; ++half) {
        int e = half * 1024 + tid * 4;           // conflict-free b128 LDS reads
        float4 s0 = *(const float4*)&lred[e];
        float4 s1 = *(const float4*)&lred[2048 + e];
        float4 s2 = *(const float4*)&lred[4096 + e];
        float4 s3 = *(const float4*)&lred[6144 + e];
        int r = e >> 7, c = e & 127;
        int n = n0 + r, b = c >> 4, d = c & 15;  // d in {0,4,8,12}: aligned float4
        float4 xi = *(const float4*)(xin + (size_t)b * BND + (size_t)n * 16 + d);
        float4 o;
        o.x = s0.x + s1.x + s2.x + s3.x + xi.x;
        o.y = s0.y + s1.y + s2.y + s3.y + xi.y;
        o.z = s0.z + s1.z + s2.z + s3.z + xi.z;
        o.w = s0.w + s1.w + s2.w + s3.w + xi.w;
        *(float4*)(Yws + ((size_t)k * NN + n) * 128 + c) = o;
    }
}

// ---------------- stage 2: out[b,n,o] = bias[o] + sum_j Y48[j] * W[o][perm(j)] ----------------
__global__ void __launch_bounds__(256) out_kernel(
    const float* __restrict__ Yws, const float* __restrict__ W,
    const float* __restrict__ bias, float* __restrict__ out)
{
    const int o   = threadIdx.x & 63;
    const int wid = blockIdx.x * 4 + (threadIdx.x >> 6);  // 2048 waves

    float wreg[48];                       // wreg[k*16+d] = W[o][d*3+k]
#pragma unroll
    for (int d = 0; d < 16; ++d)
#pragma unroll
        for (int kk = 0; kk < 3; ++kk)
            wreg[kk * 16 + d] = W[o * 48 + d * 3 + kk];
    const float bv = bias[o];

    for (int ii = 0; ii < 24; ++ii) {
        int p = wid * 24 + ii;            // p in [0, 49152)
        int b = p / NN;
        int n = p - b * NN;
        const float* yp = Yws + (size_t)n * 128 + b * 16;
        float acc = bv;
#pragma unroll
        for (int kk = 0; kk < 3; ++kk)
#pragma unroll
            for (int d4 = 0; d4 < 4; ++d4) {
                float4 y = *(const float4*)(yp + (size_t)kk * (NN * 128) + d4 * 4);
                int j = kk * 16 + d4 * 4;
                acc += y.x * wreg[j] + y.y * wreg[j + 1] + y.z * wreg[j + 2] + y.w * wreg[j + 3];
            }
        out[(size_t)p * 64 + o] = acc;
    }
}

extern "C" void kernel_launch(void* const* d_in, const int* in_sizes, int n_in,
                              void* d_out, int out_size, void* d_ws, size_t ws_size,
                              hipStream_t stream) {
    const float* xin  = (const float*)d_in[0];  // [8,6144,16]
    const float* sup  = (const float*)d_in[1];  // [3,6144,6144]
    const float* W    = (const float*)d_in[2];  // [64,48]
    const float* bias = (const float*)d_in[3];  // [64]
    float* out = (float*)d_out;                 // [8,6144,64]

    char* ws = (char*)d_ws;
    unsigned short* Xt = (unsigned short*)ws;   // 128*6144*2B = 1572864
    float* Yws = (float*)(ws + 1572864);        // 3*6144*128*4B = 9437184

    prep_kernel<<<dim3(96, 8), 256, 0, stream>>>(xin, Xt);
    gemm_kernel<<<dim3(384, 3), 256, 0, stream>>>(sup, xin, Xt, Yws);
    out_kernel<<<512, 256, 0, stream>>>(Yws, W, bias, out);
}

// Round 3
// 709.291 us; speedup vs baseline: 1.2311x; 1.2311x over previous
//
#include <hip/hip_runtime.h>

#define NN 6144
#define BND (NN*16)

typedef short short8 __attribute__((ext_vector_type(8)));
typedef float f32x4 __attribute__((ext_vector_type(4)));

__device__ __forceinline__ short f2bf(float f) {
    unsigned u = __builtin_bit_cast(unsigned, f);
    u = (u + 0x7FFFu + ((u >> 16) & 1u)) >> 16;   // RNE to bf16
    return (short)u;
}
__device__ __forceinline__ float bf2f(unsigned short s) {
    unsigned u = ((unsigned)s) << 16;
    return __builtin_bit_cast(float, u);
}

// ---------------- prep: transpose X [8,6144,16] fp32 -> Xt [128][6144] bf16 ----------------
__global__ void __launch_bounds__(256) prep_kernel(
    const float* __restrict__ xin, unsigned short* __restrict__ Xt)
{
    __shared__ unsigned short ldsT[16 * 64];
    const int b  = blockIdx.y;
    const int m0 = blockIdx.x * 64;
    const int t  = threadIdx.x;
    const int ml = t >> 2, dq = t & 3;
    float4 v = *(const float4*)(xin + (size_t)b * BND + (size_t)(m0 + ml) * 16 + dq * 4);
    ldsT[(dq * 4 + 0) * 64 + ml] = (unsigned short)f2bf(v.x);
    ldsT[(dq * 4 + 1) * 64 + ml] = (unsigned short)f2bf(v.y);
    ldsT[(dq * 4 + 2) * 64 + ml] = (unsigned short)f2bf(v.z);
    ldsT[(dq * 4 + 3) * 64 + ml] = (unsigned short)f2bf(v.w);
    __syncthreads();
    if (t < 128) {
        int d = t >> 3, j = t & 7;
        short8 s = *(const short8*)&ldsT[d * 64 + j * 8];
        *(short8*)(Xt + (size_t)(b * 16 + d) * NN + m0 + j * 8) = s;
    }
}

// ---------------- main: Ypart[seg][k][n][c] (bf16) = partial (sup_k @ X) ----------------
// Block 256 = 4 waves, tile 64 rows x 128 cols, BK=64, K-split 2 via blockIdx.z.
// A (fp32, from sup) and B (bf16, from L2-resident Xt) staged via global_load_lds with
// XOR-swizzled SOURCE addresses so fragment ds_read_b128s are ~2-way (free) without
// breaking the lane-locked LDS destination. No gathers from global anywhere.
__global__ void __launch_bounds__(256, 4) gemm_kernel(
    const float* __restrict__ sup, const unsigned short* __restrict__ Xt,
    unsigned short* __restrict__ Yp)
{
    __shared__ float ldsram[8192];                       // 32 KB
    float* ldsA = ldsram;                                // 16 KB: 64r x 16 chunks(16B) swizzled
    unsigned short* ldsB = (unsigned short*)(ldsram + 4096); // 16 KB: 128c x 8 chunks swizzled

    const int tid = threadIdx.x;
    const int w = tid >> 6, L = tid & 63, q = L >> 4, col = L & 15;
    const int n0  = blockIdx.x * 64;
    const int k   = blockIdx.y;
    const int seg = blockIdx.z;
    const float* Ab = sup + (size_t)k * NN * NN;

    f32x4 acc[8];
#pragma unroll
    for (int i = 0; i < 8; ++i) acc[i] = (f32x4)0.0f;

    for (int it = 0; it < 48; ++it) {
        const int k0 = seg * 3072 + it * 64;
        // ---- stage A: 16 KB fp32, coalesced, src-XOR-swizzled ----
#pragma unroll
        for (int i = 0; i < 4; ++i) {
            int p = i * 256 + tid;
            int r = p >> 4, cs = p & 15;
            int cch = cs ^ (r & 7);
            const float* src = Ab + (size_t)(n0 + r) * NN + k0 + cch * 4;
            __builtin_amdgcn_global_load_lds(
                (const __attribute__((address_space(1))) unsigned int*)src,
                (__attribute__((address_space(3))) unsigned int*)((char*)ldsA + p * 16), 16, 0, 0);
        }
        // ---- stage B: 16 KB bf16 from Xt (L2), coalesced, src-XOR-swizzled ----
#pragma unroll
        for (int i = 0; i < 4; ++i) {
            int p = i * 256 + tid;
            int c = p >> 3, hs = p & 7;
            int h = hs ^ (c & 7);
            const unsigned short* src = Xt + (size_t)c * NN + k0 + h * 8;
            __builtin_amdgcn_global_load_lds(
                (const __attribute__((address_space(1))) unsigned int*)src,
                (__attribute__((address_space(3))) unsigned int*)((char*)ldsB + p * 16), 16, 0, 0);
        }
        __syncthreads();   // vmcnt(0) drain: tiles ready

        const int r = w * 16 + col;   // wave w owns rows [w*16, w*16+16)
#pragma unroll
        for (int kc = 0; kc < 2; ++kc) {
            int c0 = kc * 8 + q * 2;
            float4 a0 = *(const float4*)&ldsA[(r * 16 + ((c0    ) ^ (r & 7))) * 4];
            float4 a1 = *(const float4*)&ldsA[(r * 16 + ((c0 + 1) ^ (r & 7))) * 4];
            short8 af;
            af[0] = f2bf(a0.x); af[1] = f2bf(a0.y); af[2] = f2bf(a0.z); af[3] = f2bf(a0.w);
            af[4] = f2bf(a1.x); af[5] = f2bf(a1.y); af[6] = f2bf(a1.z); af[7] = f2bf(a1.w);
#pragma unroll
            for (int cc = 0; cc < 8; ++cc) {
                int c = cc * 16 + col;
                short8 bf = *(const short8*)&ldsB[(c * 8 + ((kc * 4 + q) ^ (c & 7))) * 8];
                acc[cc] = __builtin_amdgcn_mfma_f32_16x16x32_bf16(af, bf, acc[cc], 0, 0, 0);
            }
        }
        __syncthreads();   // protect LDS before next staging
    }

    // ---- epilogue: assemble in LDS (each wave its own 8 KB region), bf16 coalesced store ----
    float* stg = ldsram + w * 2048;    // [16 rows][128 c]
#pragma unroll
    for (int cc = 0; cc < 8; ++cc)
#pragma unroll
        for (int rr = 0; rr < 4; ++rr)
            stg[(q * 4 + rr) * 128 + cc * 16 + col] = acc[cc][rr];  // C/D: col=lane&15, row=q*4+reg

    unsigned short* ypb = Yp + ((size_t)(seg * 3 + k) * NN + n0 + w * 16) * 128;
#pragma unroll
    for (int u = 0; u < 8; ++u) {
        int idx = u * 256 + L * 4;                // conflict-free float4 LDS read
        float4 v = *(const float4*)&stg[idx];
        unsigned h0 = (unsigned short)f2bf(v.x) | ((unsigned)(unsigned short)f2bf(v.y) << 16);
        unsigned h1 = (unsigned short)f2bf(v.z) | ((unsigned)(unsigned short)f2bf(v.w) << 16);
        uint2 pk; pk.x = h0; pk.y = h1;
        *(uint2*)(ypb + idx) = pk;                // rr = idx>>7, c = idx&127 folded linearly
    }
}

// ---------------- stage 2: out[b,n,o] = bias[o] + sum_{s,k,d} Yp*W' + identity ----------------
__global__ void __launch_bounds__(256) out_kernel(
    const unsigned short* __restrict__ Yp, const float* __restrict__ xin,
    const float* __restrict__ W, const float* __restrict__ bias, float* __restrict__ out)
{
    const int o   = threadIdx.x & 63;
    const int wid = blockIdx.x * 4 + (threadIdx.x >> 6);  // 2048 waves

    float wreg[48];                       // wreg[k*16+d] = W[o][d*3+k]
#pragma unroll
    for (int d = 0; d < 16; ++d)
#pragma unroll
        for (int kk = 0; kk < 3; ++kk)
            wreg[kk * 16 + d] = W[o * 48 + d * 3 + kk];
    float wsum[16];                       // identity term: sum_k wreg[k*16+d]
#pragma unroll
    for (int d = 0; d < 16; ++d) wsum[d] = wreg[d] + wreg[16 + d] + wreg[32 + d];
    const float bv = bias[o];

    for (int ii = 0; ii < 24; ++ii) {
        int p = wid * 24 + ii;            // p in [0, 49152)
        int b = p / NN;
        int n = p - b * NN;
        float acc = bv;
        const float* xp = xin + (size_t)b * BND + (size_t)n * 16;
#pragma unroll
        for (int d4 = 0; d4 < 4; ++d4) {
            float4 x4 = *(const float4*)(xp + d4 * 4);
            acc += x4.x * wsum[d4 * 4] + x4.y * wsum[d4 * 4 + 1]
                 + x4.z * wsum[d4 * 4 + 2] + x4.w * wsum[d4 * 4 + 3];
        }
#pragma unroll
        for (int s = 0; s < 2; ++s)
#pragma unroll
            for (int kk = 0; kk < 3; ++kk) {
                const unsigned short* yp = Yp + ((size_t)(s * 3 + kk) * NN + n) * 128 + b * 16;
                short8 y0 = *(const short8*)yp;
                short8 y1 = *(const short8*)(yp + 8);
#pragma unroll
                for (int j = 0; j < 8; ++j) {
                    acc += bf2f((unsigned short)y0[j]) * wreg[kk * 16 + j];
                    acc += bf2f((unsigned short)y1[j]) * wreg[kk * 16 + 8 + j];
                }
            }
        out[(size_t)p * 64 + o] = acc;
    }
}

extern "C" void kernel_launch(void* const* d_in, const int* in_sizes, int n_in,
                              void* d_out, int out_size, void* d_ws, size_t ws_size,
                              hipStream_t stream) {
    const float* xin  = (const float*)d_in[0];  // [8,6144,16]
    const float* sup  = (const float*)d_in[1];  // [3,6144,6144]
    const float* W    = (const float*)d_in[2];  // [64,48]
    const float* bias = (const float*)d_in[3];  // [64]
    float* out = (float*)d_out;                 // [8,6144,64]

    char* ws = (char*)d_ws;
    unsigned short* Xt = (unsigned short*)ws;        // 128*6144*2B = 1,572,864
    unsigned short* Yp = (unsigned short*)(ws + 1572864); // 2*3*6144*128*2B = 9,437,184

    prep_kernel<<<dim3(96, 8), 256, 0, stream>>>(xin, Xt);
    gemm_kernel<<<dim3(96, 3, 2), 256, 0, stream>>>(sup, Xt, Yp);
    out_kernel<<<512, 256, 0, stream>>>(Yp, xin, W, bias, out);
}